// Round 2
// baseline (1000.053 us; speedup 1.0000x reference)
//
#include <hip/hip_runtime.h>
#include <math.h>

#define DIM 2048
#define SEQ 2048
#define NH 16
#define NKV 8
#define HD 128
#define HIDDEN 5632
#define QKV_N 4096   // (16 + 2*8) * 128
#define FF_N 11264   // 2*HIDDEN

typedef __attribute__((ext_vector_type(8))) short s16x8;   // 8 bf16 (4 VGPRs) MFMA A/B frag
typedef __attribute__((ext_vector_type(4))) float f32x4;   // MFMA C/D frag

#define GPTR(p) ((const __attribute__((address_space(1))) void*)(p))
#define LPTR(p) ((__attribute__((address_space(3))) void*)(p))

__device__ __forceinline__ unsigned short f2bf(float f) {
    union { float f; unsigned u; } v; v.f = f;
    unsigned r = v.u + 0x7fff + ((v.u >> 16) & 1);   // RNE
    return (unsigned short)(r >> 16);
}
__device__ __forceinline__ float bf2f(unsigned short s) {
    union { unsigned u; float f; } v; v.u = ((unsigned)s) << 16;
    return v.f;
}

// ---------------- fp32 -> bf16 convert (weights) ----------------
__global__ __launch_bounds__(256) void k_cvt(const float* __restrict__ src,
                                             unsigned short* __restrict__ dst, int n4) {
    int i = blockIdx.x * 256 + threadIdx.x;
    if (i < n4) {
        float4 v = ((const float4*)src)[i];
        ushort4 o;
        o.x = f2bf(v.x); o.y = f2bf(v.y); o.z = f2bf(v.z); o.w = f2bf(v.w);
        ((ushort4*)dst)[i] = o;
    }
}

// ---------------- RMSNorm (fp32 in) -> bf16 out ----------------
__global__ __launch_bounds__(256) void k_rmsnorm(const float* __restrict__ x,
                                                 const float* __restrict__ w,
                                                 unsigned short* __restrict__ out) {
    int row = blockIdx.x;
    int tid = threadIdx.x, wv = tid >> 6, lane = tid & 63;
    const float* xr = x + (size_t)row * DIM;
    float4 a = ((const float4*)xr)[tid * 2];
    float4 b = ((const float4*)xr)[tid * 2 + 1];
    float ss = a.x*a.x + a.y*a.y + a.z*a.z + a.w*a.w
             + b.x*b.x + b.y*b.y + b.z*b.z + b.w*b.w;
    for (int off = 32; off >= 1; off >>= 1) ss += __shfl_xor(ss, off);
    __shared__ float red[4];
    if (lane == 0) red[wv] = ss;
    __syncthreads();
    float tot = red[0] + red[1] + red[2] + red[3];
    float rs = rsqrtf(tot * (1.0f / DIM) + 1e-5f);
    float4 wa = ((const float4*)w)[tid * 2];
    float4 wb = ((const float4*)w)[tid * 2 + 1];
    ushort4 o0, o1;
    o0.x = f2bf(a.x * rs * wa.x); o0.y = f2bf(a.y * rs * wa.y);
    o0.z = f2bf(a.z * rs * wa.z); o0.w = f2bf(a.w * rs * wa.w);
    o1.x = f2bf(b.x * rs * wb.x); o1.y = f2bf(b.y * rs * wb.y);
    o1.z = f2bf(b.z * rs * wb.z); o1.w = f2bf(b.w * rs * wb.w);
    ushort4* orow = (ushort4*)(out + (size_t)row * DIM);
    orow[tid * 2] = o0; orow[tid * 2 + 1] = o1;
}

// ---------------- bf16 GEMM: C[M,N] = A[M,K] @ B[N,K]^T (+fused epilogue) ----
// flags: 0 = fp32 out, 1 = fp32 out + add[] residual, 2 = bf16 out
// Grid is 1D, decoded as 128-block supertiles (16 row-tiles x 8 col-tiles)
// so concurrently-resident blocks share a ~12MB A+B strip working set (L2
// locality). Requires M == 2048 (16 row tiles) and N % 1024 == 0.
__global__ __launch_bounds__(256) void k_gemm_bt(
    const unsigned short* __restrict__ A, const unsigned short* __restrict__ B,
    int M, int N, int K,
    float* __restrict__ Cf, unsigned short* __restrict__ Cb,
    const float* __restrict__ add, int flags) {
    __shared__ __align__(16) unsigned short As[8 * 128 * 8];  // [kgrp][m][8] bf16
    __shared__ __align__(16) unsigned short Bs[8 * 128 * 8];
    int tid = threadIdx.x;
    int wv = tid >> 6, lane = tid & 63, quad = lane >> 4, l15 = lane & 15;
    int id = blockIdx.x;
    int w128 = id & 127;
    int rowBase = (w128 & 15) * 128;
    int colBase = ((id >> 7) * 8 + (w128 >> 4)) * 128;
    int wm = (wv & 1) * 64, wn = (wv >> 1) * 64;
    f32x4 acc[4][4] = {};

    for (int k0 = 0; k0 < K; k0 += 64) {
        __syncthreads();
#pragma unroll
        for (int i = 0; i < 4; i++) {
            int s = i * 256 + wv * 64 + lane;
            int kg = s >> 7, m = s & 127;
            const unsigned short* ga = A + (size_t)(rowBase + m) * K + (k0 + kg * 8);
            const unsigned short* gb = B + (size_t)(colBase + m) * K + (k0 + kg * 8);
            __builtin_amdgcn_global_load_lds(GPTR(ga), LPTR(&As[(i * 256 + wv * 64) * 8]), 16, 0, 0);
            __builtin_amdgcn_global_load_lds(GPTR(gb), LPTR(&Bs[(i * 256 + wv * 64) * 8]), 16, 0, 0);
        }
        __syncthreads();
#pragma unroll
        for (int ks = 0; ks < 2; ks++) {
            s16x8 af[4], bfr[4];
#pragma unroll
            for (int t = 0; t < 4; t++) {
                af[t]  = *(const s16x8*)&As[((ks * 4 + quad) * 128 + wm + t * 16 + l15) * 8];
                bfr[t] = *(const s16x8*)&Bs[((ks * 4 + quad) * 128 + wn + t * 16 + l15) * 8];
            }
#pragma unroll
            for (int mt = 0; mt < 4; mt++)
#pragma unroll
                for (int nt = 0; nt < 4; nt++)
                    acc[mt][nt] = __builtin_amdgcn_mfma_f32_16x16x32_bf16(af[mt], bfr[nt], acc[mt][nt], 0, 0, 0);
        }
    }
#pragma unroll
    for (int mt = 0; mt < 4; mt++)
#pragma unroll
        for (int nt = 0; nt < 4; nt++)
#pragma unroll
            for (int r = 0; r < 4; r++) {
                int row = rowBase + wm + mt * 16 + quad * 4 + r;
                int col = colBase + wn + nt * 16 + l15;
                size_t idx = (size_t)row * N + col;
                float v = acc[mt][nt][r];
                if (flags == 1) v += add[idx];
                if (flags == 2) Cb[idx] = f2bf(v);
                else            Cf[idx] = v;
            }
}

// ---------------- per-head LayerNorm + RoPE for Q and K ----------------
// One wave per (s, head). Q: writes [16][SEQ][128] bf16, pre-scaled by log2e/sqrt(128).
// K: writes fragment-contiguous global layout [kvh][kt(32)][dgrp(16)][key(64)][8].
__global__ __launch_bounds__(256) void k_qknorm_rope(
    const float* __restrict__ qkv,
    const float* __restrict__ qw, const float* __restrict__ qb,
    const float* __restrict__ kw, const float* __restrict__ kb,
    const float* __restrict__ fcos, const float* __restrict__ fsin,
    unsigned short* __restrict__ qout, unsigned short* __restrict__ kfrag) {
    int wv = threadIdx.x >> 6, lane = threadIdx.x & 63;
    int hl = blockIdx.y;              // 0..15 q-head, 16..23 k-head
    int s = blockIdx.x * 4 + wv;
    bool isq = hl < 16;
    float2 xv = *(const float2*)&qkv[(size_t)s * QKV_N + hl * HD + 2 * lane];
    float sum = xv.x + xv.y, ssq = xv.x * xv.x + xv.y * xv.y;
    for (int off = 32; off >= 1; off >>= 1) {
        sum += __shfl_xor(sum, off);
        ssq += __shfl_xor(ssq, off);
    }
    float mu = sum * (1.0f / HD);
    float var = ssq * (1.0f / HD) - mu * mu;
    float rs = rsqrtf(var + 1e-5f);
    const float* w_ = isq ? qw : kw;
    const float* b_ = isq ? qb : kb;
    float n0 = (xv.x - mu) * rs * w_[2 * lane]     + b_[2 * lane];
    float n1 = (xv.y - mu) * rs * w_[2 * lane + 1] + b_[2 * lane + 1];
    float c = fcos[s * 64 + lane], sn = fsin[s * 64 + lane];
    float o0 = n0 * c - n1 * sn;
    float o1 = n0 * sn + n1 * c;
    if (isq) {
        const float sc = 0.12751744f;  // (1/sqrt(128)) * log2(e): softmax scale + exp2 fold
        o0 *= sc; o1 *= sc;
        unsigned val = (unsigned)f2bf(o0) | ((unsigned)f2bf(o1) << 16);
        *(unsigned*)&qout[((size_t)hl * SEQ + s) * HD + 2 * lane] = val;
    } else {
        int kvh = hl - 16;
        int kt = s >> 6, key = s & 63;
        int dg = lane >> 2, j = (2 * lane) & 7;
        unsigned val = (unsigned)f2bf(o0) | ((unsigned)f2bf(o1) << 16);
        size_t idx = (((size_t)(kvh * 32 + kt) * 16 + dg) * 64 + key) * 8 + j;
        *(unsigned*)&kfrag[idx] = val;
    }
}

// ---------------- V: fp32 -> bf16, into fragment-contiguous layout -----------
// out layout: [kvh][kt(32)][kgrp(8)][d(128)][8 keys]
__global__ __launch_bounds__(256) void k_vprep(const float* __restrict__ qkv,
                                               unsigned short* __restrict__ vfrag) {
    __shared__ unsigned short lv[64][132];
    int kvh = blockIdx.y, kt = blockIdx.x, tid = threadIdx.x;
#pragma unroll
    for (int it = 0; it < 8; it++) {
        int li = it * 256 + tid;          // float4 index among 64*32
        int row = li >> 5;
        int c4 = (li & 31) * 4;
        float4 v = *(const float4*)&qkv[(size_t)(kt * 64 + row) * QKV_N + 3072 + kvh * HD + c4];
        lv[row][c4] = f2bf(v.x); lv[row][c4 + 1] = f2bf(v.y);
        lv[row][c4 + 2] = f2bf(v.z); lv[row][c4 + 3] = f2bf(v.w);
    }
    __syncthreads();
    size_t base = (size_t)(kvh * 32 + kt) * 8192;
#pragma unroll
    for (int it = 0; it < 16; it++) {
        int o2 = it * 256 + tid;          // uint index among 4096
        int e = o2 * 2;
        int r = e & 7, d = (e >> 3) & 127, kg = e >> 10;
        unsigned val = (unsigned)lv[kg * 8 + r][d] | ((unsigned)lv[kg * 8 + r + 1][d] << 16);
        *(unsigned*)&vfrag[base + e] = val;
    }
}

// ---------------- Flash attention, causal, GQA (2 q-heads per kv-head) ------
__global__ __launch_bounds__(256) void k_flash(
    const unsigned short* __restrict__ q,      // [16][SEQ][128], pre-scaled
    const unsigned short* __restrict__ kfrag,  // [8][32][16][64][8]
    const unsigned short* __restrict__ vfrag,  // [8][32][8][128][8]
    unsigned short* __restrict__ o) {          // [SEQ][2048]
    __shared__ __align__(16) unsigned short Ks[8192];
    __shared__ __align__(16) unsigned short Vs[8192];
    __shared__ __align__(16) unsigned short Ps[4][16 * 72];   // pad stride 72 (144B, 16B-aligned)
    int h = blockIdx.x & 15;
    int qt = 31 - (blockIdx.x >> 4);     // heavy (large qt) blocks launch first
    int kvh = h >> 1;
    int tid = threadIdx.x, wv = tid >> 6, lane = tid & 63, quad = lane >> 4, l15 = lane & 15;
    int qbase = qt * 64;

    s16x8 qf[4];
    {
        const unsigned short* qp = q + ((size_t)h * SEQ + qbase + wv * 16 + l15) * HD + quad * 8;
#pragma unroll
        for (int ks = 0; ks < 4; ks++) qf[ks] = *(const s16x8*)(qp + ks * 32);
    }
    f32x4 oacc[8] = {};
    float mst[4], lst[4];
#pragma unroll
    for (int r = 0; r < 4; r++) { mst[r] = -3e38f; lst[r] = 0.f; }

    for (int kt = 0; kt <= qt; kt++) {
        __syncthreads();
        size_t kb = (size_t)(kvh * 32 + kt) * 8192;
#pragma unroll
        for (int i = 0; i < 4; i++) {
            int s0 = i * 256 + wv * 64;
            __builtin_amdgcn_global_load_lds(GPTR(kfrag + kb + (size_t)(s0 + lane) * 8), LPTR(&Ks[s0 * 8]), 16, 0, 0);
            __builtin_amdgcn_global_load_lds(GPTR(vfrag + kb + (size_t)(s0 + lane) * 8), LPTR(&Vs[s0 * 8]), 16, 0, 0);
        }
        __syncthreads();

        f32x4 sacc[4];
#pragma unroll
        for (int nt = 0; nt < 4; nt++) {
            f32x4 a = {};
#pragma unroll
            for (int ks = 0; ks < 4; ks++) {
                s16x8 kf = *(const s16x8*)&Ks[((ks * 4 + quad) * 64 + nt * 16 + l15) * 8];
                a = __builtin_amdgcn_mfma_f32_16x16x32_bf16(qf[ks], kf, a, 0, 0, 0);
            }
            sacc[nt] = a;
        }
        if (kt == qt) {   // diagonal tile: mask key > query
#pragma unroll
            for (int nt = 0; nt < 4; nt++) {
                int colg = kt * 64 + nt * 16 + l15;
#pragma unroll
                for (int r = 0; r < 4; r++) {
                    int rowg = qbase + wv * 16 + quad * 4 + r;
                    if (colg > rowg) sacc[nt][r] = -3e38f;
                }
            }
        }
        unsigned short* Pw = Ps[wv];
#pragma unroll
        for (int r = 0; r < 4; r++) {
            float mx = fmaxf(fmaxf(sacc[0][r], sacc[1][r]), fmaxf(sacc[2][r], sacc[3][r]));
#pragma unroll
            for (int off = 1; off < 16; off <<= 1) mx = fmaxf(mx, __shfl_xor(mx, off));
            float mnew = fmaxf(mst[r], mx);
            float alpha = exp2f(mst[r] - mnew);
            float psum = 0.f;
#pragma unroll
            for (int nt = 0; nt < 4; nt++) {
                float p = exp2f(sacc[nt][r] - mnew);
                psum += p;
                Pw[(quad * 4 + r) * 72 + nt * 16 + l15] = f2bf(p);
            }
#pragma unroll
            for (int off = 1; off < 16; off <<= 1) psum += __shfl_xor(psum, off);
            lst[r] = lst[r] * alpha + psum;
            mst[r] = mnew;
#pragma unroll
            for (int vt = 0; vt < 8; vt++) oacc[vt][r] *= alpha;
        }
        // PV: P through LDS into A-operand layout (m120-verified transform)
#pragma unroll
        for (int ks = 0; ks < 2; ks++) {
            s16x8 pf = *(const s16x8*)&Pw[l15 * 72 + ks * 32 + quad * 8];
#pragma unroll
            for (int vt = 0; vt < 8; vt++) {
                s16x8 vf = *(const s16x8*)&Vs[((ks * 4 + quad) * 128 + vt * 16 + l15) * 8];
                oacc[vt] = __builtin_amdgcn_mfma_f32_16x16x32_bf16(pf, vf, oacc[vt], 0, 0, 0);
            }
        }
    }
#pragma unroll
    for (int r = 0; r < 4; r++) {
        float inv = 1.0f / lst[r];
        int row = qbase + wv * 16 + quad * 4 + r;
#pragma unroll
        for (int vt = 0; vt < 8; vt++)
            o[(size_t)row * DIM + h * HD + vt * 16 + l15] = f2bf(oacc[vt][r] * inv);
    }
}

// ---------------- SwiGLU: y = silu(x1) * x3 ----------------
__global__ __launch_bounds__(256) void k_silu(const unsigned short* __restrict__ x13,
                                              unsigned short* __restrict__ y) {
    int gid = blockIdx.x * 256 + threadIdx.x;     // [0, 2048*1408)
    int s = gid / 1408;
    int j4 = (gid - s * 1408) * 4;
    const unsigned short* p1 = x13 + (size_t)s * FF_N + j4;
    const unsigned short* p3 = p1 + HIDDEN;
    ushort4 a = *(const ushort4*)p1;
    ushort4 b = *(const ushort4*)p3;
    ushort4 o;
    {
        float x1 = bf2f(a.x), x3 = bf2f(b.x);
        o.x = f2bf(x1 / (1.f + __expf(-x1)) * x3);
    }
    {
        float x1 = bf2f(a.y), x3 = bf2f(b.y);
        o.y = f2bf(x1 / (1.f + __expf(-x1)) * x3);
    }
    {
        float x1 = bf2f(a.z), x3 = bf2f(b.z);
        o.z = f2bf(x1 / (1.f + __expf(-x1)) * x3);
    }
    {
        float x1 = bf2f(a.w), x3 = bf2f(b.w);
        o.w = f2bf(x1 / (1.f + __expf(-x1)) * x3);
    }
    *(ushort4*)&y[(size_t)s * HIDDEN + j4] = o;
}

extern "C" void kernel_launch(void* const* d_in, const int* in_sizes, int n_in,
                              void* d_out, int out_size, void* d_ws, size_t ws_size,
                              hipStream_t stream) {
    const float* x    = (const float*)d_in[0];
    const float* fcos = (const float*)d_in[1];
    const float* fsin = (const float*)d_in[2];
    // d_in[3] = mask: causal, implemented directly
    const float* wqkv = (const float*)d_in[4];
    const float* wo   = (const float*)d_in[5];
    const float* qn_w = (const float*)d_in[6];
    const float* qn_b = (const float*)d_in[7];
    const float* kn_w = (const float*)d_in[8];
    const float* kn_b = (const float*)d_in[9];
    const float* anw  = (const float*)d_in[10];
    const float* fnw  = (const float*)d_in[11];
    const float* w13  = (const float*)d_in[12];
    const float* w2   = (const float*)d_in[13];
    float* out = (float*)d_out;
    char* ws = (char*)d_ws;

    size_t off = 0;
    auto alloc = [&](size_t bytes) { size_t o = off; off += (bytes + 255) & ~(size_t)255; return o; };
    unsigned short* wqkv_b = (unsigned short*)(ws + alloc((size_t)QKV_N * DIM * 2));
    unsigned short* wo_b   = (unsigned short*)(ws + alloc((size_t)DIM * DIM * 2));
    unsigned short* w13_b  = (unsigned short*)(ws + alloc((size_t)FF_N * DIM * 2));
    unsigned short* w2_b   = (unsigned short*)(ws + alloc((size_t)DIM * HIDDEN * 2));
    unsigned short* xn     = (unsigned short*)(ws + alloc((size_t)SEQ * DIM * 2));
    float*          qkv    = (float*)         (ws + alloc((size_t)SEQ * QKV_N * 4));
    unsigned short* qb_    = (unsigned short*)(ws + alloc((size_t)NH * SEQ * HD * 2));
    unsigned short* kfr    = (unsigned short*)(ws + alloc((size_t)NKV * SEQ * HD * 2));
    unsigned short* vfr    = (unsigned short*)(ws + alloc((size_t)NKV * SEQ * HD * 2));
    unsigned short* ob     = (unsigned short*)(ws + alloc((size_t)SEQ * DIM * 2));
    float*          hbuf   = (float*)         (ws + alloc((size_t)SEQ * DIM * 4));
    unsigned short* gb     = (unsigned short*)(ws + alloc((size_t)SEQ * DIM * 2));
    unsigned short* x13b   = (unsigned short*)(ws + alloc((size_t)SEQ * FF_N * 2));
    unsigned short* yb     = (unsigned short*)(ws + alloc((size_t)SEQ * HIDDEN * 2));

    // weight conversions (per-call; ws is re-poisoned each launch)
    k_cvt<<<8192, 256, 0, stream>>>(wqkv, wqkv_b, QKV_N * DIM / 4);
    k_cvt<<<4096, 256, 0, stream>>>(wo, wo_b, DIM * DIM / 4);
    k_cvt<<<22528, 256, 0, stream>>>(w13, w13_b, FF_N * DIM / 4);
    k_cvt<<<11264, 256, 0, stream>>>(w2, w2_b, DIM * HIDDEN / 4);

    // h = rmsnorm(x, attn_norm_w) -> bf16
    k_rmsnorm<<<SEQ, 256, 0, stream>>>(x, anw, xn);
    // qkv = h @ wqkv^T (fp32 out)
    k_gemm_bt<<<(SEQ / 128) * (QKV_N / 128), 256, 0, stream>>>(
        xn, wqkv_b, SEQ, QKV_N, DIM, qkv, nullptr, nullptr, 0);
    // per-head LN + RoPE, write q (scaled) and k (frag layout)
    k_qknorm_rope<<<dim3(SEQ / 4, NH + NKV), 256, 0, stream>>>(
        qkv, qn_w, qn_b, kn_w, kn_b, fcos, fsin, qb_, kfr);
    // v -> bf16 frag layout
    k_vprep<<<dim3(SEQ / 64, NKV), 256, 0, stream>>>(qkv, vfr);
    // flash attention
    k_flash<<<NH * (SEQ / 64), 256, 0, stream>>>(qb_, kfr, vfr, ob);
    // h = x + o @ wo^T  (fp32)
    k_gemm_bt<<<(SEQ / 128) * (DIM / 128), 256, 0, stream>>>(
        ob, wo_b, SEQ, DIM, DIM, hbuf, nullptr, x, 1);
    // g = rmsnorm(h, ffn_norm_w) -> bf16
    k_rmsnorm<<<SEQ, 256, 0, stream>>>(hbuf, fnw, gb);
    // x13 = g @ w13^T (bf16 out)
    k_gemm_bt<<<(SEQ / 128) * (FF_N / 128), 256, 0, stream>>>(
        gb, w13_b, SEQ, FF_N, DIM, nullptr, x13b, nullptr, 2);
    // y = silu(x1) * x3
    k_silu<<<SEQ * (HIDDEN / 4) / 256, 256, 0, stream>>>(x13b, yb);
    // out = h + y @ w2^T (fp32)
    k_gemm_bt<<<(SEQ / 128) * (DIM / 128), 256, 0, stream>>>(
        yb, w2_b, SEQ, DIM, HIDDEN, out, nullptr, hbuf, 1);
}

// Round 3
// 931.600 us; speedup vs baseline: 1.0735x; 1.0735x over previous
//
#include <hip/hip_runtime.h>
#include <math.h>

#define DIM 2048
#define SEQ 2048
#define NH 16
#define NKV 8
#define HD 128
#define HIDDEN 5632
#define QKV_N 4096   // (16 + 2*8) * 128
#define FF_N 11264   // 2*HIDDEN

typedef __attribute__((ext_vector_type(8))) short s16x8;   // 8 bf16 (4 VGPRs) MFMA A/B frag
typedef __attribute__((ext_vector_type(4))) float f32x4;   // MFMA C/D frag

#define GPTR(p) ((const __attribute__((address_space(1))) void*)(p))
#define LPTR(p) ((__attribute__((address_space(3))) void*)(p))

__device__ __forceinline__ unsigned short f2bf(float f) {
    union { float f; unsigned u; } v; v.f = f;
    unsigned r = v.u + 0x7fff + ((v.u >> 16) & 1);   // RNE
    return (unsigned short)(r >> 16);
}
__device__ __forceinline__ float bf2f(unsigned short s) {
    union { unsigned u; float f; } v; v.u = ((unsigned)s) << 16;
    return v.f;
}

// ---------------- fp32 -> bf16 convert (weights) ----------------
__global__ __launch_bounds__(256) void k_cvt(const float* __restrict__ src,
                                             unsigned short* __restrict__ dst, int n4) {
    int i = blockIdx.x * 256 + threadIdx.x;
    if (i < n4) {
        float4 v = ((const float4*)src)[i];
        ushort4 o;
        o.x = f2bf(v.x); o.y = f2bf(v.y); o.z = f2bf(v.z); o.w = f2bf(v.w);
        ((ushort4*)dst)[i] = o;
    }
}

// ---------------- RMSNorm (fp32 in) -> bf16 out ----------------
__global__ __launch_bounds__(256) void k_rmsnorm(const float* __restrict__ x,
                                                 const float* __restrict__ w,
                                                 unsigned short* __restrict__ out) {
    int row = blockIdx.x;
    int tid = threadIdx.x, wv = tid >> 6, lane = tid & 63;
    const float* xr = x + (size_t)row * DIM;
    float4 a = ((const float4*)xr)[tid * 2];
    float4 b = ((const float4*)xr)[tid * 2 + 1];
    float ss = a.x*a.x + a.y*a.y + a.z*a.z + a.w*a.w
             + b.x*b.x + b.y*b.y + b.z*b.z + b.w*b.w;
    for (int off = 32; off >= 1; off >>= 1) ss += __shfl_xor(ss, off);
    __shared__ float red[4];
    if (lane == 0) red[wv] = ss;
    __syncthreads();
    float tot = red[0] + red[1] + red[2] + red[3];
    float rs = rsqrtf(tot * (1.0f / DIM) + 1e-5f);
    float4 wa = ((const float4*)w)[tid * 2];
    float4 wb = ((const float4*)w)[tid * 2 + 1];
    ushort4 o0, o1;
    o0.x = f2bf(a.x * rs * wa.x); o0.y = f2bf(a.y * rs * wa.y);
    o0.z = f2bf(a.z * rs * wa.z); o0.w = f2bf(a.w * rs * wa.w);
    o1.x = f2bf(b.x * rs * wb.x); o1.y = f2bf(b.y * rs * wb.y);
    o1.z = f2bf(b.z * rs * wb.z); o1.w = f2bf(b.w * rs * wb.w);
    ushort4* orow = (ushort4*)(out + (size_t)row * DIM);
    orow[tid * 2] = o0; orow[tid * 2 + 1] = o1;
}

// ---------------- bf16 GEMM: C[M,N] = A[M,K] @ B[N,K]^T (+fused epilogue) ----
// flags: 0 = fp32 out, 1 = fp32 out + add[] residual, 2 = bf16 out
// Double-buffered K-loop, ONE barrier per round: loads for k+1 issue after the
// barrier and drain at the NEXT barrier, so their latency hides behind compute
// of round k. (2-barrier m97 shape exposed full load latency per round.)
// Grid: x-major (col fastest). 88 % 8 == 0 => B col-strips partition across
// XCDs under round-robin dispatch (round-2 lesson: never replicate B).
__global__ __launch_bounds__(256) void k_gemm_bt(
    const unsigned short* __restrict__ A, const unsigned short* __restrict__ B,
    int M, int N, int K,
    float* __restrict__ Cf, unsigned short* __restrict__ Cb,
    const float* __restrict__ add, int flags) {
    __shared__ __align__(16) unsigned short As[2][8192];  // [buf][kgrp(8)][m(128)][8]
    __shared__ __align__(16) unsigned short Bs[2][8192];
    int tid = threadIdx.x;
    int wv = tid >> 6, lane = tid & 63, quad = lane >> 4, l15 = lane & 15;
    int rowBase = blockIdx.y * 128;
    int colBase = blockIdx.x * 128;
    int wm = (wv & 1) * 64, wn = (wv >> 1) * 64;
    f32x4 acc[4][4] = {};

    auto issue = [&](int k0, int b) {
#pragma unroll
        for (int i = 0; i < 4; i++) {
            int s = i * 256 + wv * 64 + lane;
            int kg = s >> 7, m = s & 127;
            const unsigned short* ga = A + (size_t)(rowBase + m) * K + (k0 + kg * 8);
            const unsigned short* gb = B + (size_t)(colBase + m) * K + (k0 + kg * 8);
            __builtin_amdgcn_global_load_lds(GPTR(ga), LPTR(&As[b][(i * 256 + wv * 64) * 8]), 16, 0, 0);
            __builtin_amdgcn_global_load_lds(GPTR(gb), LPTR(&Bs[b][(i * 256 + wv * 64) * 8]), 16, 0, 0);
        }
    };

    issue(0, 0);
    for (int k0 = 0; k0 < K; k0 += 64) {
        int b = (k0 >> 6) & 1;
        __syncthreads();                 // drains round-k loads (issued a full round ago)
        if (k0 + 64 < K) issue(k0 + 64, b ^ 1);
#pragma unroll
        for (int ks = 0; ks < 2; ks++) {
            s16x8 af[4], bfr[4];
#pragma unroll
            for (int t = 0; t < 4; t++) {
                af[t]  = *(const s16x8*)&As[b][((ks * 4 + quad) * 128 + wm + t * 16 + l15) * 8];
                bfr[t] = *(const s16x8*)&Bs[b][((ks * 4 + quad) * 128 + wn + t * 16 + l15) * 8];
            }
#pragma unroll
            for (int mt = 0; mt < 4; mt++)
#pragma unroll
                for (int nt = 0; nt < 4; nt++)
                    acc[mt][nt] = __builtin_amdgcn_mfma_f32_16x16x32_bf16(af[mt], bfr[nt], acc[mt][nt], 0, 0, 0);
        }
    }
#pragma unroll
    for (int mt = 0; mt < 4; mt++)
#pragma unroll
        for (int nt = 0; nt < 4; nt++)
#pragma unroll
            for (int r = 0; r < 4; r++) {
                int row = rowBase + wm + mt * 16 + quad * 4 + r;
                int col = colBase + wn + nt * 16 + l15;
                size_t idx = (size_t)row * N + col;
                float v = acc[mt][nt][r];
                if (flags == 1) v += add[idx];
                if (flags == 2) Cb[idx] = f2bf(v);
                else            Cf[idx] = v;
            }
}

// ---------------- per-head LayerNorm + RoPE for Q and K ----------------
// One wave per (s, head). Q: writes [16][SEQ][128] bf16, pre-scaled by log2e/sqrt(128).
// K: writes fragment-contiguous global layout [kvh][kt(32)][dgrp(16)][key(64)][8].
__global__ __launch_bounds__(256) void k_qknorm_rope(
    const float* __restrict__ qkv,
    const float* __restrict__ qw, const float* __restrict__ qb,
    const float* __restrict__ kw, const float* __restrict__ kb,
    const float* __restrict__ fcos, const float* __restrict__ fsin,
    unsigned short* __restrict__ qout, unsigned short* __restrict__ kfrag) {
    int wv = threadIdx.x >> 6, lane = threadIdx.x & 63;
    int hl = blockIdx.y;              // 0..15 q-head, 16..23 k-head
    int s = blockIdx.x * 4 + wv;
    bool isq = hl < 16;
    float2 xv = *(const float2*)&qkv[(size_t)s * QKV_N + hl * HD + 2 * lane];
    float sum = xv.x + xv.y, ssq = xv.x * xv.x + xv.y * xv.y;
    for (int off = 32; off >= 1; off >>= 1) {
        sum += __shfl_xor(sum, off);
        ssq += __shfl_xor(ssq, off);
    }
    float mu = sum * (1.0f / HD);
    float var = ssq * (1.0f / HD) - mu * mu;
    float rs = rsqrtf(var + 1e-5f);
    const float* w_ = isq ? qw : kw;
    const float* b_ = isq ? qb : kb;
    float n0 = (xv.x - mu) * rs * w_[2 * lane]     + b_[2 * lane];
    float n1 = (xv.y - mu) * rs * w_[2 * lane + 1] + b_[2 * lane + 1];
    float c = fcos[s * 64 + lane], sn = fsin[s * 64 + lane];
    float o0 = n0 * c - n1 * sn;
    float o1 = n0 * sn + n1 * c;
    if (isq) {
        const float sc = 0.12751744f;  // (1/sqrt(128)) * log2(e): softmax scale + exp2 fold
        o0 *= sc; o1 *= sc;
        unsigned val = (unsigned)f2bf(o0) | ((unsigned)f2bf(o1) << 16);
        *(unsigned*)&qout[((size_t)hl * SEQ + s) * HD + 2 * lane] = val;
    } else {
        int kvh = hl - 16;
        int kt = s >> 6, key = s & 63;
        int dg = lane >> 2, j = (2 * lane) & 7;
        unsigned val = (unsigned)f2bf(o0) | ((unsigned)f2bf(o1) << 16);
        size_t idx = (((size_t)(kvh * 32 + kt) * 16 + dg) * 64 + key) * 8 + j;
        *(unsigned*)&kfrag[idx] = val;
    }
}

// ---------------- V: fp32 -> bf16, into fragment-contiguous layout -----------
// out layout: [kvh][kt(32)][kgrp(8)][d(128)][8 keys]
__global__ __launch_bounds__(256) void k_vprep(const float* __restrict__ qkv,
                                               unsigned short* __restrict__ vfrag) {
    __shared__ unsigned short lv[64][132];
    int kvh = blockIdx.y, kt = blockIdx.x, tid = threadIdx.x;
#pragma unroll
    for (int it = 0; it < 8; it++) {
        int li = it * 256 + tid;          // float4 index among 64*32
        int row = li >> 5;
        int c4 = (li & 31) * 4;
        float4 v = *(const float4*)&qkv[(size_t)(kt * 64 + row) * QKV_N + 3072 + kvh * HD + c4];
        lv[row][c4] = f2bf(v.x); lv[row][c4 + 1] = f2bf(v.y);
        lv[row][c4 + 2] = f2bf(v.z); lv[row][c4 + 3] = f2bf(v.w);
    }
    __syncthreads();
    size_t base = (size_t)(kvh * 32 + kt) * 8192;
#pragma unroll
    for (int it = 0; it < 16; it++) {
        int o2 = it * 256 + tid;          // uint index among 4096
        int e = o2 * 2;
        int r = e & 7, d = (e >> 3) & 127, kg = e >> 10;
        unsigned val = (unsigned)lv[kg * 8 + r][d] | ((unsigned)lv[kg * 8 + r + 1][d] << 16);
        *(unsigned*)&vfrag[base + e] = val;
    }
}

// ---------------- Flash attention, causal, GQA (2 q-heads per kv-head) ------
// Double-buffered K/V staging: loads for kt+1 issue after the barrier, drain
// at the next barrier (hidden behind QK+softmax+PV compute of round kt).
__global__ __launch_bounds__(256) void k_flash(
    const unsigned short* __restrict__ q,      // [16][SEQ][128], pre-scaled
    const unsigned short* __restrict__ kfrag,  // [8][32][16][64][8]
    const unsigned short* __restrict__ vfrag,  // [8][32][8][128][8]
    unsigned short* __restrict__ o) {          // [SEQ][2048]
    __shared__ __align__(16) unsigned short Ks[2][8192];
    __shared__ __align__(16) unsigned short Vs[2][8192];
    __shared__ __align__(16) unsigned short Ps[4][16 * 72];   // pad stride 72 (144B, 16B-aligned)
    int h = blockIdx.x & 15;
    int qt = 31 - (blockIdx.x >> 4);     // heavy (large qt) blocks launch first
    int kvh = h >> 1;
    int tid = threadIdx.x, wv = tid >> 6, lane = tid & 63, quad = lane >> 4, l15 = lane & 15;
    int qbase = qt * 64;

    s16x8 qf[4];
    {
        const unsigned short* qp = q + ((size_t)h * SEQ + qbase + wv * 16 + l15) * HD + quad * 8;
#pragma unroll
        for (int ks = 0; ks < 4; ks++) qf[ks] = *(const s16x8*)(qp + ks * 32);
    }
    f32x4 oacc[8] = {};
    float mst[4], lst[4];
#pragma unroll
    for (int r = 0; r < 4; r++) { mst[r] = -3e38f; lst[r] = 0.f; }

    auto issueKV = [&](int kt, int b) {
        size_t kb = (size_t)(kvh * 32 + kt) * 8192;
#pragma unroll
        for (int i = 0; i < 4; i++) {
            int s0 = i * 256 + wv * 64;
            __builtin_amdgcn_global_load_lds(GPTR(kfrag + kb + (size_t)(s0 + lane) * 8), LPTR(&Ks[b][s0 * 8]), 16, 0, 0);
            __builtin_amdgcn_global_load_lds(GPTR(vfrag + kb + (size_t)(s0 + lane) * 8), LPTR(&Vs[b][s0 * 8]), 16, 0, 0);
        }
    };

    issueKV(0, 0);
    for (int kt = 0; kt <= qt; kt++) {
        int b = kt & 1;
        __syncthreads();
        if (kt < qt) issueKV(kt + 1, b ^ 1);

        f32x4 sacc[4];
#pragma unroll
        for (int nt = 0; nt < 4; nt++) {
            f32x4 a = {};
#pragma unroll
            for (int ks = 0; ks < 4; ks++) {
                s16x8 kf = *(const s16x8*)&Ks[b][((ks * 4 + quad) * 64 + nt * 16 + l15) * 8];
                a = __builtin_amdgcn_mfma_f32_16x16x32_bf16(qf[ks], kf, a, 0, 0, 0);
            }
            sacc[nt] = a;
        }
        if (kt == qt) {   // diagonal tile: mask key > query
#pragma unroll
            for (int nt = 0; nt < 4; nt++) {
                int colg = kt * 64 + nt * 16 + l15;
#pragma unroll
                for (int r = 0; r < 4; r++) {
                    int rowg = qbase + wv * 16 + quad * 4 + r;
                    if (colg > rowg) sacc[nt][r] = -3e38f;
                }
            }
        }
        unsigned short* Pw = Ps[wv];
#pragma unroll
        for (int r = 0; r < 4; r++) {
            float mx = fmaxf(fmaxf(sacc[0][r], sacc[1][r]), fmaxf(sacc[2][r], sacc[3][r]));
#pragma unroll
            for (int off = 1; off < 16; off <<= 1) mx = fmaxf(mx, __shfl_xor(mx, off));
            float mnew = fmaxf(mst[r], mx);
            float alpha = exp2f(mst[r] - mnew);
            float psum = 0.f;
#pragma unroll
            for (int nt = 0; nt < 4; nt++) {
                float p = exp2f(sacc[nt][r] - mnew);
                psum += p;
                Pw[(quad * 4 + r) * 72 + nt * 16 + l15] = f2bf(p);
            }
#pragma unroll
            for (int off = 1; off < 16; off <<= 1) psum += __shfl_xor(psum, off);
            lst[r] = lst[r] * alpha + psum;
            mst[r] = mnew;
#pragma unroll
            for (int vt = 0; vt < 8; vt++) oacc[vt][r] *= alpha;
        }
        // PV: P through LDS into A-operand layout (m120-verified transform)
#pragma unroll
        for (int ks = 0; ks < 2; ks++) {
            s16x8 pf = *(const s16x8*)&Pw[l15 * 72 + ks * 32 + quad * 8];
#pragma unroll
            for (int vt = 0; vt < 8; vt++) {
                s16x8 vf = *(const s16x8*)&Vs[b][((ks * 4 + quad) * 128 + vt * 16 + l15) * 8];
                oacc[vt] = __builtin_amdgcn_mfma_f32_16x16x32_bf16(pf, vf, oacc[vt], 0, 0, 0);
            }
        }
    }
#pragma unroll
    for (int r = 0; r < 4; r++) {
        float inv = 1.0f / lst[r];
        int row = qbase + wv * 16 + quad * 4 + r;
#pragma unroll
        for (int vt = 0; vt < 8; vt++)
            o[(size_t)row * DIM + h * HD + vt * 16 + l15] = f2bf(oacc[vt][r] * inv);
    }
}

// ---------------- SwiGLU: y = silu(x1) * x3 ----------------
__global__ __launch_bounds__(256) void k_silu(const unsigned short* __restrict__ x13,
                                              unsigned short* __restrict__ y) {
    int gid = blockIdx.x * 256 + threadIdx.x;     // [0, 2048*1408)
    int s = gid / 1408;
    int j4 = (gid - s * 1408) * 4;
    const unsigned short* p1 = x13 + (size_t)s * FF_N + j4;
    const unsigned short* p3 = p1 + HIDDEN;
    ushort4 a = *(const ushort4*)p1;
    ushort4 b = *(const ushort4*)p3;
    ushort4 o;
    {
        float x1 = bf2f(a.x), x3 = bf2f(b.x);
        o.x = f2bf(x1 / (1.f + __expf(-x1)) * x3);
    }
    {
        float x1 = bf2f(a.y), x3 = bf2f(b.y);
        o.y = f2bf(x1 / (1.f + __expf(-x1)) * x3);
    }
    {
        float x1 = bf2f(a.z), x3 = bf2f(b.z);
        o.z = f2bf(x1 / (1.f + __expf(-x1)) * x3);
    }
    {
        float x1 = bf2f(a.w), x3 = bf2f(b.w);
        o.w = f2bf(x1 / (1.f + __expf(-x1)) * x3);
    }
    *(ushort4*)&y[(size_t)s * HIDDEN + j4] = o;
}

extern "C" void kernel_launch(void* const* d_in, const int* in_sizes, int n_in,
                              void* d_out, int out_size, void* d_ws, size_t ws_size,
                              hipStream_t stream) {
    const float* x    = (const float*)d_in[0];
    const float* fcos = (const float*)d_in[1];
    const float* fsin = (const float*)d_in[2];
    // d_in[3] = mask: causal, implemented directly
    const float* wqkv = (const float*)d_in[4];
    const float* wo   = (const float*)d_in[5];
    const float* qn_w = (const float*)d_in[6];
    const float* qn_b = (const float*)d_in[7];
    const float* kn_w = (const float*)d_in[8];
    const float* kn_b = (const float*)d_in[9];
    const float* anw  = (const float*)d_in[10];
    const float* fnw  = (const float*)d_in[11];
    const float* w13  = (const float*)d_in[12];
    const float* w2   = (const float*)d_in[13];
    float* out = (float*)d_out;
    char* ws = (char*)d_ws;

    size_t off = 0;
    auto alloc = [&](size_t bytes) { size_t o = off; off += (bytes + 255) & ~(size_t)255; return o; };
    unsigned short* wqkv_b = (unsigned short*)(ws + alloc((size_t)QKV_N * DIM * 2));
    unsigned short* wo_b   = (unsigned short*)(ws + alloc((size_t)DIM * DIM * 2));
    unsigned short* w13_b  = (unsigned short*)(ws + alloc((size_t)FF_N * DIM * 2));
    unsigned short* w2_b   = (unsigned short*)(ws + alloc((size_t)DIM * HIDDEN * 2));
    unsigned short* xn     = (unsigned short*)(ws + alloc((size_t)SEQ * DIM * 2));
    float*          qkv    = (float*)         (ws + alloc((size_t)SEQ * QKV_N * 4));
    unsigned short* qb_    = (unsigned short*)(ws + alloc((size_t)NH * SEQ * HD * 2));
    unsigned short* kfr    = (unsigned short*)(ws + alloc((size_t)NKV * SEQ * HD * 2));
    unsigned short* vfr    = (unsigned short*)(ws + alloc((size_t)NKV * SEQ * HD * 2));
    unsigned short* ob     = (unsigned short*)(ws + alloc((size_t)SEQ * DIM * 2));
    float*          hbuf   = (float*)         (ws + alloc((size_t)SEQ * DIM * 4));
    unsigned short* gb     = (unsigned short*)(ws + alloc((size_t)SEQ * DIM * 2));
    unsigned short* x13b   = (unsigned short*)(ws + alloc((size_t)SEQ * FF_N * 2));
    unsigned short* yb     = (unsigned short*)(ws + alloc((size_t)SEQ * HIDDEN * 2));

    // weight conversions (per-call; ws is re-poisoned each launch)
    k_cvt<<<8192, 256, 0, stream>>>(wqkv, wqkv_b, QKV_N * DIM / 4);
    k_cvt<<<4096, 256, 0, stream>>>(wo, wo_b, DIM * DIM / 4);
    k_cvt<<<22528, 256, 0, stream>>>(w13, w13_b, FF_N * DIM / 4);
    k_cvt<<<11264, 256, 0, stream>>>(w2, w2_b, DIM * HIDDEN / 4);

    // h = rmsnorm(x, attn_norm_w) -> bf16
    k_rmsnorm<<<SEQ, 256, 0, stream>>>(x, anw, xn);
    // qkv = h @ wqkv^T (fp32 out)
    k_gemm_bt<<<dim3(QKV_N / 128, SEQ / 128), 256, 0, stream>>>(
        xn, wqkv_b, SEQ, QKV_N, DIM, qkv, nullptr, nullptr, 0);
    // per-head LN + RoPE, write q (scaled) and k (frag layout)
    k_qknorm_rope<<<dim3(SEQ / 4, NH + NKV), 256, 0, stream>>>(
        qkv, qn_w, qn_b, kn_w, kn_b, fcos, fsin, qb_, kfr);
    // v -> bf16 frag layout
    k_vprep<<<dim3(SEQ / 64, NKV), 256, 0, stream>>>(qkv, vfr);
    // flash attention
    k_flash<<<NH * (SEQ / 64), 256, 0, stream>>>(qb_, kfr, vfr, ob);
    // h = x + o @ wo^T  (fp32)
    k_gemm_bt<<<dim3(DIM / 128, SEQ / 128), 256, 0, stream>>>(
        ob, wo_b, SEQ, DIM, DIM, hbuf, nullptr, x, 1);
    // g = rmsnorm(h, ffn_norm_w) -> bf16
    k_rmsnorm<<<SEQ, 256, 0, stream>>>(hbuf, fnw, gb);
    // x13 = g @ w13^T (bf16 out)
    k_gemm_bt<<<dim3(FF_N / 128, SEQ / 128), 256, 0, stream>>>(
        gb, w13_b, SEQ, FF_N, DIM, nullptr, x13b, nullptr, 2);
    // y = silu(x1) * x3
    k_silu<<<SEQ * (HIDDEN / 4) / 256, 256, 0, stream>>>(x13b, yb);
    // out = h + y @ w2^T (fp32)
    k_gemm_bt<<<dim3(DIM / 128, SEQ / 128), 256, 0, stream>>>(
        yb, w2_b, SEQ, DIM, HIDDEN, out, nullptr, hbuf, 1);
}

// Round 4
// 895.735 us; speedup vs baseline: 1.1165x; 1.0400x over previous
//
#include <hip/hip_runtime.h>
#include <math.h>

#define DIM 2048
#define SEQ 2048
#define NH 16
#define NKV 8
#define HD 128
#define HIDDEN 5632
#define QKV_N 4096   // (16 + 2*8) * 128
#define FF_N 11264   // 2*HIDDEN

typedef __attribute__((ext_vector_type(8))) short s16x8;   // 8 bf16 (4 VGPRs) MFMA A/B frag
typedef __attribute__((ext_vector_type(4))) float f32x4;   // MFMA C/D frag

#define GPTR(p) ((const __attribute__((address_space(1))) void*)(p))
#define LPTR(p) ((__attribute__((address_space(3))) void*)(p))

__device__ __forceinline__ unsigned short f2bf(float f) {
    union { float f; unsigned u; } v; v.f = f;
    unsigned r = v.u + 0x7fff + ((v.u >> 16) & 1);   // RNE
    return (unsigned short)(r >> 16);
}
__device__ __forceinline__ float bf2f(unsigned short s) {
    union { unsigned u; float f; } v; v.u = ((unsigned)s) << 16;
    return v.f;
}

// ---------------- fp32 -> bf16 convert (weights) ----------------
__global__ __launch_bounds__(256) void k_cvt(const float* __restrict__ src,
                                             unsigned short* __restrict__ dst, int n4) {
    int i = blockIdx.x * 256 + threadIdx.x;
    if (i < n4) {
        float4 v = ((const float4*)src)[i];
        ushort4 o;
        o.x = f2bf(v.x); o.y = f2bf(v.y); o.z = f2bf(v.z); o.w = f2bf(v.w);
        ((ushort4*)dst)[i] = o;
    }
}

// ---------------- RMSNorm (fp32 in) -> bf16 out ----------------
__global__ __launch_bounds__(256) void k_rmsnorm(const float* __restrict__ x,
                                                 const float* __restrict__ w,
                                                 unsigned short* __restrict__ out) {
    int row = blockIdx.x;
    int tid = threadIdx.x, wv = tid >> 6, lane = tid & 63;
    const float* xr = x + (size_t)row * DIM;
    float4 a = ((const float4*)xr)[tid * 2];
    float4 b = ((const float4*)xr)[tid * 2 + 1];
    float ss = a.x*a.x + a.y*a.y + a.z*a.z + a.w*a.w
             + b.x*b.x + b.y*b.y + b.z*b.z + b.w*b.w;
    for (int off = 32; off >= 1; off >>= 1) ss += __shfl_xor(ss, off);
    __shared__ float red[4];
    if (lane == 0) red[wv] = ss;
    __syncthreads();
    float tot = red[0] + red[1] + red[2] + red[3];
    float rs = rsqrtf(tot * (1.0f / DIM) + 1e-5f);
    float4 wa = ((const float4*)w)[tid * 2];
    float4 wb = ((const float4*)w)[tid * 2 + 1];
    ushort4 o0, o1;
    o0.x = f2bf(a.x * rs * wa.x); o0.y = f2bf(a.y * rs * wa.y);
    o0.z = f2bf(a.z * rs * wa.z); o0.w = f2bf(a.w * rs * wa.w);
    o1.x = f2bf(b.x * rs * wb.x); o1.y = f2bf(b.y * rs * wb.y);
    o1.z = f2bf(b.z * rs * wb.z); o1.w = f2bf(b.w * rs * wb.w);
    ushort4* orow = (ushort4*)(out + (size_t)row * DIM);
    orow[tid * 2] = o0; orow[tid * 2 + 1] = o1;
}

// ---------------- bf16 GEMM: C[M,N] = A[M,K] @ B[N,K]^T (+fused epilogue) ----
// flags: 0 = fp32 out, 1 = fp32 out + add[] residual, 2 = bf16 out
// Single-buffer 2-barrier K-loop (round-1 measured best for this structure;
// dbuf was neutral-to-worse — m99/m131-141 pattern). X-major grid: 8 | gridDim.x
// => B col-strips partition across XCDs (FETCH floor = B*1 + A*8, verified R1).
// Kslice + blockIdx.z implement split-K for low-block-count GEMMs (N=2048:
// 256 blocks = 1 block/CU has zero inter-block latency overlap; split-K *2
// doubles resident blocks). Partial z writes to Cf + z*M*N, fp32, flags=0.
__global__ __launch_bounds__(256) void k_gemm_bt(
    const unsigned short* __restrict__ A, const unsigned short* __restrict__ B,
    int M, int N, int K, int Kslice,
    float* __restrict__ Cf, unsigned short* __restrict__ Cb,
    const float* __restrict__ add, int flags) {
    __shared__ __align__(16) unsigned short As[8192];  // [kgrp(8)][m(128)][8]
    __shared__ __align__(16) unsigned short Bs[8192];
    int tid = threadIdx.x;
    int wv = tid >> 6, lane = tid & 63, quad = lane >> 4, l15 = lane & 15;
    int rowBase = blockIdx.y * 128;
    int colBase = blockIdx.x * 128;
    int kb = blockIdx.z * Kslice, ke = kb + Kslice;
    int wm = (wv & 1) * 64, wn = (wv >> 1) * 64;
    f32x4 acc[4][4] = {};

    for (int k0 = kb; k0 < ke; k0 += 64) {
        __syncthreads();
#pragma unroll
        for (int i = 0; i < 4; i++) {
            int s = i * 256 + wv * 64 + lane;
            int kg = s >> 7, m = s & 127;
            const unsigned short* ga = A + (size_t)(rowBase + m) * K + (k0 + kg * 8);
            const unsigned short* gb = B + (size_t)(colBase + m) * K + (k0 + kg * 8);
            __builtin_amdgcn_global_load_lds(GPTR(ga), LPTR(&As[(i * 256 + wv * 64) * 8]), 16, 0, 0);
            __builtin_amdgcn_global_load_lds(GPTR(gb), LPTR(&Bs[(i * 256 + wv * 64) * 8]), 16, 0, 0);
        }
        __syncthreads();
#pragma unroll
        for (int ks = 0; ks < 2; ks++) {
            s16x8 af[4], bfr[4];
#pragma unroll
            for (int t = 0; t < 4; t++) {
                af[t]  = *(const s16x8*)&As[((ks * 4 + quad) * 128 + wm + t * 16 + l15) * 8];
                bfr[t] = *(const s16x8*)&Bs[((ks * 4 + quad) * 128 + wn + t * 16 + l15) * 8];
            }
#pragma unroll
            for (int mt = 0; mt < 4; mt++)
#pragma unroll
                for (int nt = 0; nt < 4; nt++)
                    acc[mt][nt] = __builtin_amdgcn_mfma_f32_16x16x32_bf16(af[mt], bfr[nt], acc[mt][nt], 0, 0, 0);
        }
    }
    float* Cfz = Cf ? Cf + (size_t)blockIdx.z * M * N : Cf;
#pragma unroll
    for (int mt = 0; mt < 4; mt++)
#pragma unroll
        for (int nt = 0; nt < 4; nt++)
#pragma unroll
            for (int r = 0; r < 4; r++) {
                int row = rowBase + wm + mt * 16 + quad * 4 + r;
                int col = colBase + wn + nt * 16 + l15;
                size_t idx = (size_t)row * N + col;
                float v = acc[mt][nt][r];
                if (flags == 1) v += add[idx];
                if (flags == 2) Cb[idx] = f2bf(v);
                else            Cfz[idx] = v;
            }
}

// ---------------- 3-way add (split-K reduce + residual) ----------------
__global__ __launch_bounds__(256) void k_red3(const float* __restrict__ a,
                                              const float* __restrict__ b,
                                              const float* __restrict__ c,
                                              float* __restrict__ o, int n4) {
    int i = blockIdx.x * 256 + threadIdx.x;
    if (i < n4) {
        float4 x = ((const float4*)a)[i];
        float4 y = ((const float4*)b)[i];
        float4 z = ((const float4*)c)[i];
        float4 r;
        r.x = x.x + y.x + z.x; r.y = x.y + y.y + z.y;
        r.z = x.z + y.z + z.z; r.w = x.w + y.w + z.w;
        ((float4*)o)[i] = r;
    }
}

// ---------------- per-head LayerNorm + RoPE for Q and K ----------------
// One wave per (s, head). Q: writes [16][SEQ][128] bf16, pre-scaled by log2e/sqrt(128).
// K: writes fragment-contiguous global layout [kvh][kt(32)][dgrp(16)][key(64)][8].
__global__ __launch_bounds__(256) void k_qknorm_rope(
    const float* __restrict__ qkv,
    const float* __restrict__ qw, const float* __restrict__ qb,
    const float* __restrict__ kw, const float* __restrict__ kb,
    const float* __restrict__ fcos, const float* __restrict__ fsin,
    unsigned short* __restrict__ qout, unsigned short* __restrict__ kfrag) {
    int wv = threadIdx.x >> 6, lane = threadIdx.x & 63;
    int hl = blockIdx.y;              // 0..15 q-head, 16..23 k-head
    int s = blockIdx.x * 4 + wv;
    bool isq = hl < 16;
    float2 xv = *(const float2*)&qkv[(size_t)s * QKV_N + hl * HD + 2 * lane];
    float sum = xv.x + xv.y, ssq = xv.x * xv.x + xv.y * xv.y;
    for (int off = 32; off >= 1; off >>= 1) {
        sum += __shfl_xor(sum, off);
        ssq += __shfl_xor(ssq, off);
    }
    float mu = sum * (1.0f / HD);
    float var = ssq * (1.0f / HD) - mu * mu;
    float rs = rsqrtf(var + 1e-5f);
    const float* w_ = isq ? qw : kw;
    const float* b_ = isq ? qb : kb;
    float n0 = (xv.x - mu) * rs * w_[2 * lane]     + b_[2 * lane];
    float n1 = (xv.y - mu) * rs * w_[2 * lane + 1] + b_[2 * lane + 1];
    float c = fcos[s * 64 + lane], sn = fsin[s * 64 + lane];
    float o0 = n0 * c - n1 * sn;
    float o1 = n0 * sn + n1 * c;
    if (isq) {
        const float sc = 0.12751744f;  // (1/sqrt(128)) * log2(e): softmax scale + exp2 fold
        o0 *= sc; o1 *= sc;
        unsigned val = (unsigned)f2bf(o0) | ((unsigned)f2bf(o1) << 16);
        *(unsigned*)&qout[((size_t)hl * SEQ + s) * HD + 2 * lane] = val;
    } else {
        int kvh = hl - 16;
        int kt = s >> 6, key = s & 63;
        int dg = lane >> 2, j = (2 * lane) & 7;
        unsigned val = (unsigned)f2bf(o0) | ((unsigned)f2bf(o1) << 16);
        size_t idx = (((size_t)(kvh * 32 + kt) * 16 + dg) * 64 + key) * 8 + j;
        *(unsigned*)&kfrag[idx] = val;
    }
}

// ---------------- V: fp32 -> bf16, into fragment-contiguous layout -----------
// out layout: [kvh][kt(32)][kgrp(8)][d(128)][8 keys]
__global__ __launch_bounds__(256) void k_vprep(const float* __restrict__ qkv,
                                               unsigned short* __restrict__ vfrag) {
    __shared__ unsigned short lv[64][132];
    int kvh = blockIdx.y, kt = blockIdx.x, tid = threadIdx.x;
#pragma unroll
    for (int it = 0; it < 8; it++) {
        int li = it * 256 + tid;          // float4 index among 64*32
        int row = li >> 5;
        int c4 = (li & 31) * 4;
        float4 v = *(const float4*)&qkv[(size_t)(kt * 64 + row) * QKV_N + 3072 + kvh * HD + c4];
        lv[row][c4] = f2bf(v.x); lv[row][c4 + 1] = f2bf(v.y);
        lv[row][c4 + 2] = f2bf(v.z); lv[row][c4 + 3] = f2bf(v.w);
    }
    __syncthreads();
    size_t base = (size_t)(kvh * 32 + kt) * 8192;
#pragma unroll
    for (int it = 0; it < 16; it++) {
        int o2 = it * 256 + tid;          // uint index among 4096
        int e = o2 * 2;
        int r = e & 7, d = (e >> 3) & 127, kg = e >> 10;
        unsigned val = (unsigned)lv[kg * 8 + r][d] | ((unsigned)lv[kg * 8 + r + 1][d] << 16);
        *(unsigned*)&vfrag[base + e] = val;
    }
}

// ---------------- Flash attention, causal, GQA (2 q-heads per kv-head) ------
// Double-buffered K/V staging (kept from R3: at 1-ish block/CU the intra-block
// overlap is the only overlap, and R3 total improved with it).
__global__ __launch_bounds__(256) void k_flash(
    const unsigned short* __restrict__ q,      // [16][SEQ][128], pre-scaled
    const unsigned short* __restrict__ kfrag,  // [8][32][16][64][8]
    const unsigned short* __restrict__ vfrag,  // [8][32][8][128][8]
    unsigned short* __restrict__ o) {          // [SEQ][2048]
    __shared__ __align__(16) unsigned short Ks[2][8192];
    __shared__ __align__(16) unsigned short Vs[2][8192];
    __shared__ __align__(16) unsigned short Ps[4][16 * 72];   // pad stride 72 (144B, 16B-aligned)
    int h = blockIdx.x & 15;
    int qt = 31 - (blockIdx.x >> 4);     // heavy (large qt) blocks launch first
    int kvh = h >> 1;
    int tid = threadIdx.x, wv = tid >> 6, lane = tid & 63, quad = lane >> 4, l15 = lane & 15;
    int qbase = qt * 64;

    s16x8 qf[4];
    {
        const unsigned short* qp = q + ((size_t)h * SEQ + qbase + wv * 16 + l15) * HD + quad * 8;
#pragma unroll
        for (int ks = 0; ks < 4; ks++) qf[ks] = *(const s16x8*)(qp + ks * 32);
    }
    f32x4 oacc[8] = {};
    float mst[4], lst[4];
#pragma unroll
    for (int r = 0; r < 4; r++) { mst[r] = -3e38f; lst[r] = 0.f; }

    auto issueKV = [&](int kt, int b) {
        size_t kb = (size_t)(kvh * 32 + kt) * 8192;
#pragma unroll
        for (int i = 0; i < 4; i++) {
            int s0 = i * 256 + wv * 64;
            __builtin_amdgcn_global_load_lds(GPTR(kfrag + kb + (size_t)(s0 + lane) * 8), LPTR(&Ks[b][s0 * 8]), 16, 0, 0);
            __builtin_amdgcn_global_load_lds(GPTR(vfrag + kb + (size_t)(s0 + lane) * 8), LPTR(&Vs[b][s0 * 8]), 16, 0, 0);
        }
    };

    issueKV(0, 0);
    for (int kt = 0; kt <= qt; kt++) {
        int b = kt & 1;
        __syncthreads();
        if (kt < qt) issueKV(kt + 1, b ^ 1);

        f32x4 sacc[4];
#pragma unroll
        for (int nt = 0; nt < 4; nt++) {
            f32x4 a = {};
#pragma unroll
            for (int ks = 0; ks < 4; ks++) {
                s16x8 kf = *(const s16x8*)&Ks[b][((ks * 4 + quad) * 64 + nt * 16 + l15) * 8];
                a = __builtin_amdgcn_mfma_f32_16x16x32_bf16(qf[ks], kf, a, 0, 0, 0);
            }
            sacc[nt] = a;
        }
        if (kt == qt) {   // diagonal tile: mask key > query
#pragma unroll
            for (int nt = 0; nt < 4; nt++) {
                int colg = kt * 64 + nt * 16 + l15;
#pragma unroll
                for (int r = 0; r < 4; r++) {
                    int rowg = qbase + wv * 16 + quad * 4 + r;
                    if (colg > rowg) sacc[nt][r] = -3e38f;
                }
            }
        }
        unsigned short* Pw = Ps[wv];
#pragma unroll
        for (int r = 0; r < 4; r++) {
            float mx = fmaxf(fmaxf(sacc[0][r], sacc[1][r]), fmaxf(sacc[2][r], sacc[3][r]));
#pragma unroll
            for (int off = 1; off < 16; off <<= 1) mx = fmaxf(mx, __shfl_xor(mx, off));
            float mnew = fmaxf(mst[r], mx);
            float alpha = exp2f(mst[r] - mnew);
            float psum = 0.f;
#pragma unroll
            for (int nt = 0; nt < 4; nt++) {
                float p = exp2f(sacc[nt][r] - mnew);
                psum += p;
                Pw[(quad * 4 + r) * 72 + nt * 16 + l15] = f2bf(p);
            }
#pragma unroll
            for (int off = 1; off < 16; off <<= 1) psum += __shfl_xor(psum, off);
            lst[r] = lst[r] * alpha + psum;
            mst[r] = mnew;
#pragma unroll
            for (int vt = 0; vt < 8; vt++) oacc[vt][r] *= alpha;
        }
        // PV: P through LDS into A-operand layout (m120-verified transform)
#pragma unroll
        for (int ks = 0; ks < 2; ks++) {
            s16x8 pf = *(const s16x8*)&Pw[l15 * 72 + ks * 32 + quad * 8];
#pragma unroll
            for (int vt = 0; vt < 8; vt++) {
                s16x8 vf = *(const s16x8*)&Vs[b][((ks * 4 + quad) * 128 + vt * 16 + l15) * 8];
                oacc[vt] = __builtin_amdgcn_mfma_f32_16x16x32_bf16(pf, vf, oacc[vt], 0, 0, 0);
            }
        }
    }
#pragma unroll
    for (int r = 0; r < 4; r++) {
        float inv = 1.0f / lst[r];
        int row = qbase + wv * 16 + quad * 4 + r;
#pragma unroll
        for (int vt = 0; vt < 8; vt++)
            o[(size_t)row * DIM + h * HD + vt * 16 + l15] = f2bf(oacc[vt][r] * inv);
    }
}

// ---------------- SwiGLU: y = silu(x1) * x3 ----------------
__global__ __launch_bounds__(256) void k_silu(const unsigned short* __restrict__ x13,
                                              unsigned short* __restrict__ y) {
    int gid = blockIdx.x * 256 + threadIdx.x;     // [0, 2048*1408)
    int s = gid / 1408;
    int j4 = (gid - s * 1408) * 4;
    const unsigned short* p1 = x13 + (size_t)s * FF_N + j4;
    const unsigned short* p3 = p1 + HIDDEN;
    ushort4 a = *(const ushort4*)p1;
    ushort4 b = *(const ushort4*)p3;
    ushort4 o;
    {
        float x1 = bf2f(a.x), x3 = bf2f(b.x);
        o.x = f2bf(x1 / (1.f + __expf(-x1)) * x3);
    }
    {
        float x1 = bf2f(a.y), x3 = bf2f(b.y);
        o.y = f2bf(x1 / (1.f + __expf(-x1)) * x3);
    }
    {
        float x1 = bf2f(a.z), x3 = bf2f(b.z);
        o.z = f2bf(x1 / (1.f + __expf(-x1)) * x3);
    }
    {
        float x1 = bf2f(a.w), x3 = bf2f(b.w);
        o.w = f2bf(x1 / (1.f + __expf(-x1)) * x3);
    }
    *(ushort4*)&y[(size_t)s * HIDDEN + j4] = o;
}

extern "C" void kernel_launch(void* const* d_in, const int* in_sizes, int n_in,
                              void* d_out, int out_size, void* d_ws, size_t ws_size,
                              hipStream_t stream) {
    const float* x    = (const float*)d_in[0];
    const float* fcos = (const float*)d_in[1];
    const float* fsin = (const float*)d_in[2];
    // d_in[3] = mask: causal, implemented directly
    const float* wqkv = (const float*)d_in[4];
    const float* wo   = (const float*)d_in[5];
    const float* qn_w = (const float*)d_in[6];
    const float* qn_b = (const float*)d_in[7];
    const float* kn_w = (const float*)d_in[8];
    const float* kn_b = (const float*)d_in[9];
    const float* anw  = (const float*)d_in[10];
    const float* fnw  = (const float*)d_in[11];
    const float* w13  = (const float*)d_in[12];
    const float* w2   = (const float*)d_in[13];
    float* out = (float*)d_out;
    char* ws = (char*)d_ws;

    size_t off = 0;
    auto alloc = [&](size_t bytes) { size_t o = off; off += (bytes + 255) & ~(size_t)255; return o; };
    unsigned short* wqkv_b = (unsigned short*)(ws + alloc((size_t)QKV_N * DIM * 2));
    unsigned short* wo_b   = (unsigned short*)(ws + alloc((size_t)DIM * DIM * 2));
    unsigned short* w13_b  = (unsigned short*)(ws + alloc((size_t)FF_N * DIM * 2));
    unsigned short* w2_b   = (unsigned short*)(ws + alloc((size_t)DIM * HIDDEN * 2));
    unsigned short* xn     = (unsigned short*)(ws + alloc((size_t)SEQ * DIM * 2));
    float*          qkv    = (float*)         (ws + alloc((size_t)SEQ * QKV_N * 4));
    unsigned short* qb_    = (unsigned short*)(ws + alloc((size_t)NH * SEQ * HD * 2));
    unsigned short* kfr    = (unsigned short*)(ws + alloc((size_t)NKV * SEQ * HD * 2));
    unsigned short* vfr    = (unsigned short*)(ws + alloc((size_t)NKV * SEQ * HD * 2));
    unsigned short* ob     = (unsigned short*)(ws + alloc((size_t)SEQ * DIM * 2));
    float*          hbuf   = (float*)         (ws + alloc((size_t)SEQ * DIM * 4));
    unsigned short* gb     = (unsigned short*)(ws + alloc((size_t)SEQ * DIM * 2));
    unsigned short* x13b   = (unsigned short*)(ws + alloc((size_t)SEQ * FF_N * 2));
    unsigned short* yb     = (unsigned short*)(ws + alloc((size_t)SEQ * HIDDEN * 2));
    float*          p0     = (float*)         (ws + alloc((size_t)SEQ * DIM * 4));
    float*          p1     = (float*)         (ws + alloc((size_t)SEQ * DIM * 4));

    // weight conversions (per-call; ws is re-poisoned each launch)
    k_cvt<<<8192, 256, 0, stream>>>(wqkv, wqkv_b, QKV_N * DIM / 4);
    k_cvt<<<4096, 256, 0, stream>>>(wo, wo_b, DIM * DIM / 4);
    k_cvt<<<22528, 256, 0, stream>>>(w13, w13_b, FF_N * DIM / 4);
    k_cvt<<<11264, 256, 0, stream>>>(w2, w2_b, DIM * HIDDEN / 4);

    // h = rmsnorm(x, attn_norm_w) -> bf16
    k_rmsnorm<<<SEQ, 256, 0, stream>>>(x, anw, xn);
    // qkv = h @ wqkv^T (fp32 out)
    k_gemm_bt<<<dim3(QKV_N / 128, SEQ / 128), 256, 0, stream>>>(
        xn, wqkv_b, SEQ, QKV_N, DIM, DIM, qkv, nullptr, nullptr, 0);
    // per-head LN + RoPE, write q (scaled) and k (frag layout)
    k_qknorm_rope<<<dim3(SEQ / 4, NH + NKV), 256, 0, stream>>>(
        qkv, qn_w, qn_b, kn_w, kn_b, fcos, fsin, qb_, kfr);
    // v -> bf16 frag layout
    k_vprep<<<dim3(SEQ / 64, NKV), 256, 0, stream>>>(qkv, vfr);
    // flash attention
    k_flash<<<NH * (SEQ / 64), 256, 0, stream>>>(qb_, kfr, vfr, ob);
    // attn proj, split-K x2: p0/p1 = ob @ wo^T halves; hbuf = x + p0 + p1
    k_gemm_bt<<<dim3(DIM / 128, SEQ / 128, 2), 256, 0, stream>>>(
        ob, wo_b, SEQ, DIM, DIM, DIM / 2, p0, nullptr, nullptr, 0);
    k_red3<<<SEQ * DIM / 1024, 256, 0, stream>>>(p0, p1, x, hbuf, SEQ * DIM / 4);
    // g = rmsnorm(h, ffn_norm_w) -> bf16
    k_rmsnorm<<<SEQ, 256, 0, stream>>>(hbuf, fnw, gb);
    // x13 = g @ w13^T (bf16 out)
    k_gemm_bt<<<dim3(FF_N / 128, SEQ / 128), 256, 0, stream>>>(
        gb, w13_b, SEQ, FF_N, DIM, DIM, nullptr, x13b, nullptr, 2);
    // y = silu(x1) * x3
    k_silu<<<SEQ * (HIDDEN / 4) / 256, 256, 0, stream>>>(x13b, yb);
    // FFN down, split-K x2: p0/p1 = yb @ w2^T halves; out = hbuf + p0 + p1
    k_gemm_bt<<<dim3(DIM / 128, SEQ / 128, 2), 256, 0, stream>>>(
        yb, w2_b, SEQ, DIM, HIDDEN, HIDDEN / 2, p0, nullptr, nullptr, 0);
    k_red3<<<SEQ * DIM / 1024, 256, 0, stream>>>(p0, p1, hbuf, out, SEQ * DIM / 4);
}

// Round 5
// 887.662 us; speedup vs baseline: 1.1266x; 1.0091x over previous
//
#include <hip/hip_runtime.h>
#include <math.h>

#define DIM 2048
#define SEQ 2048
#define NH 16
#define NKV 8
#define HD 128
#define HIDDEN 5632
#define QKV_N 4096   // (16 + 2*8) * 128
#define FF_N 11264   // 2*HIDDEN

typedef __attribute__((ext_vector_type(8))) short s16x8;   // 8 bf16 (4 VGPRs) MFMA A/B frag
typedef __attribute__((ext_vector_type(4))) float f32x4;   // MFMA C/D frag

#define GPTR(p) ((const __attribute__((address_space(1))) void*)(p))
#define LPTR(p) ((__attribute__((address_space(3))) void*)(p))

__device__ __forceinline__ unsigned short f2bf(float f) {
    union { float f; unsigned u; } v; v.f = f;
    unsigned r = v.u + 0x7fff + ((v.u >> 16) & 1);   // RNE
    return (unsigned short)(r >> 16);
}
__device__ __forceinline__ float bf2f(unsigned short s) {
    union { unsigned u; float f; } v; v.u = ((unsigned)s) << 16;
    return v.f;
}

// ---------------- fp32 -> bf16 convert (weights) ----------------
__global__ __launch_bounds__(256) void k_cvt(const float* __restrict__ src,
                                             unsigned short* __restrict__ dst, int n4) {
    int i = blockIdx.x * 256 + threadIdx.x;
    if (i < n4) {
        float4 v = ((const float4*)src)[i];
        ushort4 o;
        o.x = f2bf(v.x); o.y = f2bf(v.y); o.z = f2bf(v.z); o.w = f2bf(v.w);
        ((ushort4*)dst)[i] = o;
    }
}

// ---------------- RMSNorm (fp32 in) -> bf16 out ----------------
__global__ __launch_bounds__(256) void k_rmsnorm(const float* __restrict__ x,
                                                 const float* __restrict__ w,
                                                 unsigned short* __restrict__ out) {
    int row = blockIdx.x;
    int tid = threadIdx.x, wv = tid >> 6, lane = tid & 63;
    const float* xr = x + (size_t)row * DIM;
    float4 a = ((const float4*)xr)[tid * 2];
    float4 b = ((const float4*)xr)[tid * 2 + 1];
    float ss = a.x*a.x + a.y*a.y + a.z*a.z + a.w*a.w
             + b.x*b.x + b.y*b.y + b.z*b.z + b.w*b.w;
    for (int off = 32; off >= 1; off >>= 1) ss += __shfl_xor(ss, off);
    __shared__ float red[4];
    if (lane == 0) red[wv] = ss;
    __syncthreads();
    float tot = red[0] + red[1] + red[2] + red[3];
    float rs = rsqrtf(tot * (1.0f / DIM) + 1e-5f);
    float4 wa = ((const float4*)w)[tid * 2];
    float4 wb = ((const float4*)w)[tid * 2 + 1];
    ushort4 o0, o1;
    o0.x = f2bf(a.x * rs * wa.x); o0.y = f2bf(a.y * rs * wa.y);
    o0.z = f2bf(a.z * rs * wa.z); o0.w = f2bf(a.w * rs * wa.w);
    o1.x = f2bf(b.x * rs * wb.x); o1.y = f2bf(b.y * rs * wb.y);
    o1.z = f2bf(b.z * rs * wb.z); o1.w = f2bf(b.w * rs * wb.w);
    ushort4* orow = (ushort4*)(out + (size_t)row * DIM);
    orow[tid * 2] = o0; orow[tid * 2 + 1] = o1;
}

// ---------------- bf16 GEMM: C[M,N] = A[M,K] @ B[N,K]^T (+fused epilogue) ----
// flags: 0 = fp32 out (at Cf + z*M*N for split-K), 1 = +add residual, 2 = bf16.
// __launch_bounds__(256,4): target 4 waves/EU = 4 blocks/CU (128-reg budget;
// acc=64 AGPR + lean operand loop ~20 live VGPR). R1-R4 showed 2-3 blocks/CU
// leaves vmcnt(0) drains uncovered (3340 cyc/block-round vs m97's 1475 at 4).
// ID template only disambiguates rocprof dispatch names per GEMM instance.
template<int ID>
__global__ __launch_bounds__(256, 4) void k_gemm_bt(
    const unsigned short* __restrict__ A, const unsigned short* __restrict__ B,
    int M, int N, int K, int Kslice,
    float* __restrict__ Cf, unsigned short* __restrict__ Cb,
    const float* __restrict__ add, int flags) {
    __shared__ __align__(16) unsigned short As[8192];  // [kgrp(8)][m(128)][8]
    __shared__ __align__(16) unsigned short Bs[8192];
    int tid = threadIdx.x;
    int wv = tid >> 6, lane = tid & 63, quad = lane >> 4, l15 = lane & 15;
    int rowBase = blockIdx.y * 128;
    int colBase = blockIdx.x * 128;
    int kb = blockIdx.z * Kslice, ke = kb + Kslice;
    int wm = (wv & 1) * 64, wn = (wv >> 1) * 64;
    f32x4 acc[4][4] = {};

    for (int k0 = kb; k0 < ke; k0 += 64) {
        __syncthreads();
#pragma unroll
        for (int i = 0; i < 4; i++) {
            int s = i * 256 + wv * 64 + lane;
            int kg = s >> 7, m = s & 127;
            const unsigned short* ga = A + (size_t)(rowBase + m) * K + (k0 + kg * 8);
            const unsigned short* gb = B + (size_t)(colBase + m) * K + (k0 + kg * 8);
            __builtin_amdgcn_global_load_lds(GPTR(ga), LPTR(&As[(i * 256 + wv * 64) * 8]), 16, 0, 0);
            __builtin_amdgcn_global_load_lds(GPTR(gb), LPTR(&Bs[(i * 256 + wv * 64) * 8]), 16, 0, 0);
        }
        __syncthreads();
#pragma unroll
        for (int ks = 0; ks < 2; ks++) {
            s16x8 bfr[4];
#pragma unroll
            for (int t = 0; t < 4; t++)
                bfr[t] = *(const s16x8*)&Bs[((ks * 4 + quad) * 128 + wn + t * 16 + l15) * 8];
#pragma unroll
            for (int mt = 0; mt < 4; mt++) {
                s16x8 af = *(const s16x8*)&As[((ks * 4 + quad) * 128 + wm + mt * 16 + l15) * 8];
#pragma unroll
                for (int nt = 0; nt < 4; nt++)
                    acc[mt][nt] = __builtin_amdgcn_mfma_f32_16x16x32_bf16(af, bfr[nt], acc[mt][nt], 0, 0, 0);
            }
        }
    }
    float* Cfz = Cf ? Cf + (size_t)blockIdx.z * M * N : Cf;
#pragma unroll
    for (int mt = 0; mt < 4; mt++)
#pragma unroll
        for (int nt = 0; nt < 4; nt++)
#pragma unroll
            for (int r = 0; r < 4; r++) {
                int row = rowBase + wm + mt * 16 + quad * 4 + r;
                int col = colBase + wn + nt * 16 + l15;
                size_t idx = (size_t)row * N + col;
                float v = acc[mt][nt][r];
                if (flags == 1) v += add[idx];
                if (flags == 2) Cb[idx] = f2bf(v);
                else            Cfz[idx] = v;
            }
}

// ---------------- 5-way add (split-K x4 reduce + residual) ----------------
__global__ __launch_bounds__(256) void k_red5(const float* __restrict__ p,
                                              size_t pstride,
                                              const float* __restrict__ res,
                                              float* __restrict__ o, int n4) {
    int i = blockIdx.x * 256 + threadIdx.x;
    if (i < n4) {
        float4 r = ((const float4*)res)[i];
#pragma unroll
        for (int z = 0; z < 4; z++) {
            float4 v = ((const float4*)(p + z * pstride))[i];
            r.x += v.x; r.y += v.y; r.z += v.z; r.w += v.w;
        }
        ((float4*)o)[i] = r;
    }
}

// ---------------- per-head LayerNorm + RoPE for Q and K ----------------
// One wave per (s, head). Q: writes [16][SEQ][128] bf16, pre-scaled by log2e/sqrt(128).
// K: writes fragment-contiguous global layout [kvh][kt(32)][dgrp(16)][key(64)][8].
__global__ __launch_bounds__(256) void k_qknorm_rope(
    const float* __restrict__ qkv,
    const float* __restrict__ qw, const float* __restrict__ qb,
    const float* __restrict__ kw, const float* __restrict__ kb,
    const float* __restrict__ fcos, const float* __restrict__ fsin,
    unsigned short* __restrict__ qout, unsigned short* __restrict__ kfrag) {
    int wv = threadIdx.x >> 6, lane = threadIdx.x & 63;
    int hl = blockIdx.y;              // 0..15 q-head, 16..23 k-head
    int s = blockIdx.x * 4 + wv;
    bool isq = hl < 16;
    float2 xv = *(const float2*)&qkv[(size_t)s * QKV_N + hl * HD + 2 * lane];
    float sum = xv.x + xv.y, ssq = xv.x * xv.x + xv.y * xv.y;
    for (int off = 32; off >= 1; off >>= 1) {
        sum += __shfl_xor(sum, off);
        ssq += __shfl_xor(ssq, off);
    }
    float mu = sum * (1.0f / HD);
    float var = ssq * (1.0f / HD) - mu * mu;
    float rs = rsqrtf(var + 1e-5f);
    const float* w_ = isq ? qw : kw;
    const float* b_ = isq ? qb : kb;
    float n0 = (xv.x - mu) * rs * w_[2 * lane]     + b_[2 * lane];
    float n1 = (xv.y - mu) * rs * w_[2 * lane + 1] + b_[2 * lane + 1];
    float c = fcos[s * 64 + lane], sn = fsin[s * 64 + lane];
    float o0 = n0 * c - n1 * sn;
    float o1 = n0 * sn + n1 * c;
    if (isq) {
        const float sc = 0.12751744f;  // (1/sqrt(128)) * log2(e): softmax scale + exp2 fold
        o0 *= sc; o1 *= sc;
        unsigned val = (unsigned)f2bf(o0) | ((unsigned)f2bf(o1) << 16);
        *(unsigned*)&qout[((size_t)hl * SEQ + s) * HD + 2 * lane] = val;
    } else {
        int kvh = hl - 16;
        int kt = s >> 6, key = s & 63;
        int dg = lane >> 2, j = (2 * lane) & 7;
        unsigned val = (unsigned)f2bf(o0) | ((unsigned)f2bf(o1) << 16);
        size_t idx = (((size_t)(kvh * 32 + kt) * 16 + dg) * 64 + key) * 8 + j;
        *(unsigned*)&kfrag[idx] = val;
    }
}

// ---------------- V: fp32 -> bf16, into fragment-contiguous layout -----------
// out layout: [kvh][kt(32)][kgrp(8)][d(128)][8 keys]
__global__ __launch_bounds__(256) void k_vprep(const float* __restrict__ qkv,
                                               unsigned short* __restrict__ vfrag) {
    __shared__ unsigned short lv[64][132];
    int kvh = blockIdx.y, kt = blockIdx.x, tid = threadIdx.x;
#pragma unroll
    for (int it = 0; it < 8; it++) {
        int li = it * 256 + tid;          // float4 index among 64*32
        int row = li >> 5;
        int c4 = (li & 31) * 4;
        float4 v = *(const float4*)&qkv[(size_t)(kt * 64 + row) * QKV_N + 3072 + kvh * HD + c4];
        lv[row][c4] = f2bf(v.x); lv[row][c4 + 1] = f2bf(v.y);
        lv[row][c4 + 2] = f2bf(v.z); lv[row][c4 + 3] = f2bf(v.w);
    }
    __syncthreads();
    size_t base = (size_t)(kvh * 32 + kt) * 8192;
#pragma unroll
    for (int it = 0; it < 16; it++) {
        int o2 = it * 256 + tid;          // uint index among 4096
        int e = o2 * 2;
        int r = e & 7, d = (e >> 3) & 127, kg = e >> 10;
        unsigned val = (unsigned)lv[kg * 8 + r][d] | ((unsigned)lv[kg * 8 + r + 1][d] << 16);
        *(unsigned*)&vfrag[base + e] = val;
    }
}

// ---------------- Flash attention, causal, GQA (2 q-heads per kv-head) ------
// Double-buffered K/V staging (kept from R3: at 1-ish block/CU the intra-block
// overlap is the only overlap, and R3 total improved with it).
__global__ __launch_bounds__(256) void k_flash(
    const unsigned short* __restrict__ q,      // [16][SEQ][128], pre-scaled
    const unsigned short* __restrict__ kfrag,  // [8][32][16][64][8]
    const unsigned short* __restrict__ vfrag,  // [8][32][8][128][8]
    unsigned short* __restrict__ o) {          // [SEQ][2048]
    __shared__ __align__(16) unsigned short Ks[2][8192];
    __shared__ __align__(16) unsigned short Vs[2][8192];
    __shared__ __align__(16) unsigned short Ps[4][16 * 72];   // pad stride 72 (144B, 16B-aligned)
    int h = blockIdx.x & 15;
    int qt = 31 - (blockIdx.x >> 4);     // heavy (large qt) blocks launch first
    int kvh = h >> 1;
    int tid = threadIdx.x, wv = tid >> 6, lane = tid & 63, quad = lane >> 4, l15 = lane & 15;
    int qbase = qt * 64;

    s16x8 qf[4];
    {
        const unsigned short* qp = q + ((size_t)h * SEQ + qbase + wv * 16 + l15) * HD + quad * 8;
#pragma unroll
        for (int ks = 0; ks < 4; ks++) qf[ks] = *(const s16x8*)(qp + ks * 32);
    }
    f32x4 oacc[8] = {};
    float mst[4], lst[4];
#pragma unroll
    for (int r = 0; r < 4; r++) { mst[r] = -3e38f; lst[r] = 0.f; }

    auto issueKV = [&](int kt, int b) {
        size_t kb = (size_t)(kvh * 32 + kt) * 8192;
#pragma unroll
        for (int i = 0; i < 4; i++) {
            int s0 = i * 256 + wv * 64;
            __builtin_amdgcn_global_load_lds(GPTR(kfrag + kb + (size_t)(s0 + lane) * 8), LPTR(&Ks[b][s0 * 8]), 16, 0, 0);
            __builtin_amdgcn_global_load_lds(GPTR(vfrag + kb + (size_t)(s0 + lane) * 8), LPTR(&Vs[b][s0 * 8]), 16, 0, 0);
        }
    };

    issueKV(0, 0);
    for (int kt = 0; kt <= qt; kt++) {
        int b = kt & 1;
        __syncthreads();
        if (kt < qt) issueKV(kt + 1, b ^ 1);

        f32x4 sacc[4];
#pragma unroll
        for (int nt = 0; nt < 4; nt++) {
            f32x4 a = {};
#pragma unroll
            for (int ks = 0; ks < 4; ks++) {
                s16x8 kf = *(const s16x8*)&Ks[b][((ks * 4 + quad) * 64 + nt * 16 + l15) * 8];
                a = __builtin_amdgcn_mfma_f32_16x16x32_bf16(qf[ks], kf, a, 0, 0, 0);
            }
            sacc[nt] = a;
        }
        if (kt == qt) {   // diagonal tile: mask key > query
#pragma unroll
            for (int nt = 0; nt < 4; nt++) {
                int colg = kt * 64 + nt * 16 + l15;
#pragma unroll
                for (int r = 0; r < 4; r++) {
                    int rowg = qbase + wv * 16 + quad * 4 + r;
                    if (colg > rowg) sacc[nt][r] = -3e38f;
                }
            }
        }
        unsigned short* Pw = Ps[wv];
#pragma unroll
        for (int r = 0; r < 4; r++) {
            float mx = fmaxf(fmaxf(sacc[0][r], sacc[1][r]), fmaxf(sacc[2][r], sacc[3][r]));
#pragma unroll
            for (int off = 1; off < 16; off <<= 1) mx = fmaxf(mx, __shfl_xor(mx, off));
            float mnew = fmaxf(mst[r], mx);
            float alpha = exp2f(mst[r] - mnew);
            float psum = 0.f;
#pragma unroll
            for (int nt = 0; nt < 4; nt++) {
                float p = exp2f(sacc[nt][r] - mnew);
                psum += p;
                Pw[(quad * 4 + r) * 72 + nt * 16 + l15] = f2bf(p);
            }
#pragma unroll
            for (int off = 1; off < 16; off <<= 1) psum += __shfl_xor(psum, off);
            lst[r] = lst[r] * alpha + psum;
            mst[r] = mnew;
#pragma unroll
            for (int vt = 0; vt < 8; vt++) oacc[vt][r] *= alpha;
        }
        // PV: P through LDS into A-operand layout (m120-verified transform)
#pragma unroll
        for (int ks = 0; ks < 2; ks++) {
            s16x8 pf = *(const s16x8*)&Pw[l15 * 72 + ks * 32 + quad * 8];
#pragma unroll
            for (int vt = 0; vt < 8; vt++) {
                s16x8 vf = *(const s16x8*)&Vs[b][((ks * 4 + quad) * 128 + vt * 16 + l15) * 8];
                oacc[vt] = __builtin_amdgcn_mfma_f32_16x16x32_bf16(pf, vf, oacc[vt], 0, 0, 0);
            }
        }
    }
#pragma unroll
    for (int r = 0; r < 4; r++) {
        float inv = 1.0f / lst[r];
        int row = qbase + wv * 16 + quad * 4 + r;
#pragma unroll
        for (int vt = 0; vt < 8; vt++)
            o[(size_t)row * DIM + h * HD + vt * 16 + l15] = f2bf(oacc[vt][r] * inv);
    }
}

// ---------------- SwiGLU: y = silu(x1) * x3 ----------------
__global__ __launch_bounds__(256) void k_silu(const unsigned short* __restrict__ x13,
                                              unsigned short* __restrict__ y) {
    int gid = blockIdx.x * 256 + threadIdx.x;     // [0, 2048*1408)
    int s = gid / 1408;
    int j4 = (gid - s * 1408) * 4;
    const unsigned short* p1 = x13 + (size_t)s * FF_N + j4;
    const unsigned short* p3 = p1 + HIDDEN;
    ushort4 a = *(const ushort4*)p1;
    ushort4 b = *(const ushort4*)p3;
    ushort4 o;
    {
        float x1 = bf2f(a.x), x3 = bf2f(b.x);
        o.x = f2bf(x1 / (1.f + __expf(-x1)) * x3);
    }
    {
        float x1 = bf2f(a.y), x3 = bf2f(b.y);
        o.y = f2bf(x1 / (1.f + __expf(-x1)) * x3);
    }
    {
        float x1 = bf2f(a.z), x3 = bf2f(b.z);
        o.z = f2bf(x1 / (1.f + __expf(-x1)) * x3);
    }
    {
        float x1 = bf2f(a.w), x3 = bf2f(b.w);
        o.w = f2bf(x1 / (1.f + __expf(-x1)) * x3);
    }
    *(ushort4*)&y[(size_t)s * HIDDEN + j4] = o;
}

extern "C" void kernel_launch(void* const* d_in, const int* in_sizes, int n_in,
                              void* d_out, int out_size, void* d_ws, size_t ws_size,
                              hipStream_t stream) {
    const float* x    = (const float*)d_in[0];
    const float* fcos = (const float*)d_in[1];
    const float* fsin = (const float*)d_in[2];
    // d_in[3] = mask: causal, implemented directly
    const float* wqkv = (const float*)d_in[4];
    const float* wo   = (const float*)d_in[5];
    const float* qn_w = (const float*)d_in[6];
    const float* qn_b = (const float*)d_in[7];
    const float* kn_w = (const float*)d_in[8];
    const float* kn_b = (const float*)d_in[9];
    const float* anw  = (const float*)d_in[10];
    const float* fnw  = (const float*)d_in[11];
    const float* w13  = (const float*)d_in[12];
    const float* w2   = (const float*)d_in[13];
    float* out = (float*)d_out;
    char* ws = (char*)d_ws;

    size_t off = 0;
    auto alloc = [&](size_t bytes) { size_t o = off; off += (bytes + 255) & ~(size_t)255; return o; };
    unsigned short* wqkv_b = (unsigned short*)(ws + alloc((size_t)QKV_N * DIM * 2));
    unsigned short* wo_b   = (unsigned short*)(ws + alloc((size_t)DIM * DIM * 2));
    unsigned short* w13_b  = (unsigned short*)(ws + alloc((size_t)FF_N * DIM * 2));
    unsigned short* w2_b   = (unsigned short*)(ws + alloc((size_t)DIM * HIDDEN * 2));
    unsigned short* xn     = (unsigned short*)(ws + alloc((size_t)SEQ * DIM * 2));
    float*          qkv    = (float*)         (ws + alloc((size_t)SEQ * QKV_N * 4));
    unsigned short* qb_    = (unsigned short*)(ws + alloc((size_t)NH * SEQ * HD * 2));
    unsigned short* kfr    = (unsigned short*)(ws + alloc((size_t)NKV * SEQ * HD * 2));
    unsigned short* vfr    = (unsigned short*)(ws + alloc((size_t)NKV * SEQ * HD * 2));
    unsigned short* ob     = (unsigned short*)(ws + alloc((size_t)SEQ * DIM * 2));
    float*          hbuf   = (float*)         (ws + alloc((size_t)SEQ * DIM * 4));
    unsigned short* gb     = (unsigned short*)(ws + alloc((size_t)SEQ * DIM * 2));
    unsigned short* x13b   = (unsigned short*)(ws + alloc((size_t)SEQ * FF_N * 2));
    unsigned short* yb     = (unsigned short*)(ws + alloc((size_t)SEQ * HIDDEN * 2));
    float*          pp     = (float*)         (ws + alloc((size_t)4 * SEQ * DIM * 4));
    const size_t pstride = (size_t)SEQ * DIM;

    // weight conversions (per-call; ws is re-poisoned each launch)
    k_cvt<<<8192, 256, 0, stream>>>(wqkv, wqkv_b, QKV_N * DIM / 4);
    k_cvt<<<4096, 256, 0, stream>>>(wo, wo_b, DIM * DIM / 4);
    k_cvt<<<22528, 256, 0, stream>>>(w13, w13_b, FF_N * DIM / 4);
    k_cvt<<<11264, 256, 0, stream>>>(w2, w2_b, DIM * HIDDEN / 4);

    // h = rmsnorm(x, attn_norm_w) -> bf16
    k_rmsnorm<<<SEQ, 256, 0, stream>>>(x, anw, xn);
    // qkv = h @ wqkv^T (fp32 out)
    k_gemm_bt<0><<<dim3(QKV_N / 128, SEQ / 128), 256, 0, stream>>>(
        xn, wqkv_b, SEQ, QKV_N, DIM, DIM, qkv, nullptr, nullptr, 0);
    // per-head LN + RoPE, write q (scaled) and k (frag layout)
    k_qknorm_rope<<<dim3(SEQ / 4, NH + NKV), 256, 0, stream>>>(
        qkv, qn_w, qn_b, kn_w, kn_b, fcos, fsin, qb_, kfr);
    // v -> bf16 frag layout
    k_vprep<<<dim3(SEQ / 64, NKV), 256, 0, stream>>>(qkv, vfr);
    // flash attention
    k_flash<<<NH * (SEQ / 64), 256, 0, stream>>>(qb_, kfr, vfr, ob);
    // attn proj, split-K x4; hbuf = x + sum(partials)
    k_gemm_bt<1><<<dim3(DIM / 128, SEQ / 128, 4), 256, 0, stream>>>(
        ob, wo_b, SEQ, DIM, DIM, DIM / 4, pp, nullptr, nullptr, 0);
    k_red5<<<SEQ * DIM / 1024, 256, 0, stream>>>(pp, pstride, x, hbuf, SEQ * DIM / 4);
    // g = rmsnorm(h, ffn_norm_w) -> bf16
    k_rmsnorm<<<SEQ, 256, 0, stream>>>(hbuf, fnw, gb);
    // x13 = g @ w13^T (bf16 out)
    k_gemm_bt<2><<<dim3(FF_N / 128, SEQ / 128), 256, 0, stream>>>(
        gb, w13_b, SEQ, FF_N, DIM, DIM, nullptr, x13b, nullptr, 2);
    // y = silu(x1) * x3
    k_silu<<<SEQ * (HIDDEN / 4) / 256, 256, 0, stream>>>(x13b, yb);
    // FFN down, split-K x4; out = hbuf + sum(partials)
    k_gemm_bt<3><<<dim3(DIM / 128, SEQ / 128, 4), 256, 0, stream>>>(
        yb, w2_b, SEQ, DIM, HIDDEN, HIDDEN / 4, pp, nullptr, nullptr, 0);
    k_red5<<<SEQ * DIM / 1024, 256, 0, stream>>>(pp, pstride, hbuf, out, SEQ * DIM / 4);
}